// Round 1
// baseline (314.798 us; speedup 1.0000x reference)
//
#include <hip/hip_runtime.h>
#include <float.h>
#include <limits.h>

#define MEMN 65536
#define WD 128
#define KSEL 8
#define RD 9
#define BD 32
#define IND 512
#define IFACE 266
#define XI_STRIDE 272   // pad 266 -> 272 floats so each batch row is 16B-aligned

#define NCHUNK 128
#define ROWS_PER_CHUNK 512
#define GROUPS 8
#define CAND_SCAN (NCHUNK * GROUPS * 8)   // 8192
#define CAND_REAL (CAND_SCAN + RD)        // 8201
#define CAND_PER_BATCH 8208               // padded

// Sorted ascending (val, idx) top-8 insert; fully unrolled -> registers only.
#define TOP8_INSERT(bv, bi, vin, iin)                                  \
  { float _v = (vin); int _i = (iin);                                  \
    _Pragma("unroll")                                                  \
    for (int _j = 0; _j < 8; ++_j) {                                   \
      bool _b = (_v < bv[_j]) || (_v == bv[_j] && _i < bi[_j]);        \
      float _tv = bv[_j]; int _ti = bi[_j];                            \
      bv[_j] = _b ? _v : _tv;  bi[_j] = _b ? _i : _ti;                 \
      _v = _b ? _tv : _v;      _i = _b ? _ti : _i;                     \
    } }

__global__ __launch_bounds__(320)
void xi_kernel(const float* __restrict__ x, const float* __restrict__ Wif,
               const float* __restrict__ bif, float* __restrict__ xi) {
  const int b = blockIdx.x;
  const int c = threadIdx.x;
  if (c >= IFACE) return;
  float acc = bif[c];
  const float* xr = x + b * IND;
  for (int k = 0; k < IND; ++k)
    acc += xr[k] * Wif[k * IFACE + c];
  xi[b * XI_STRIDE + c] = acc;
}

__global__ __launch_bounds__(WD)
void prep_kernel(const float* __restrict__ xi, const float* __restrict__ read_weights,
                 const float* __restrict__ read_vectors, float* __restrict__ new_rv) {
  const int b = blockIdx.x;
  const int t = threadIdx.x;   // 128
  __shared__ float ww[RD];
  if (t < RD) {
    float g  = 1.f / (1.f + __expf(-xi[b * XI_STRIDE + 2 * WD + t]));
    float wg = 1.f / (1.f + __expf(-xi[b * XI_STRIDE + (IFACE - 1)]));
    float rw = read_weights[b * RD + t];
    ww[t] = wg * (g * rw + (1.f - g));
  }
  __syncthreads();
  const float wv = xi[b * XI_STRIDE + WD + t];
  #pragma unroll
  for (int r = 0; r < RD; ++r)
    new_rv[(b * RD + r) * WD + t] = read_vectors[(b * RD + r) * WD + t] + ww[r] * wv;
}

__global__ __launch_bounds__(64)
void fixup_kernel(const float* __restrict__ xi, const float* __restrict__ new_rv,
                  const int* __restrict__ rpos,
                  float* __restrict__ cand_val, int* __restrict__ cand_idx) {
  const int b = blockIdx.x;
  const int lane = threadIdx.x;   // 64
  const float q0 = xi[b * XI_STRIDE + lane * 2];
  const float q1 = xi[b * XI_STRIDE + lane * 2 + 1];
  for (int r = 0; r < RD; ++r) {
    const float* row = new_rv + (b * RD + r) * WD;
    float m0 = row[lane * 2], m1 = row[lane * 2 + 1];
    float s = m0 * (m0 - 2.f * q0) + m1 * (m1 - 2.f * q1);
    #pragma unroll
    for (int off = 32; off; off >>= 1) s += __shfl_xor(s, off);
    if (lane == 0) {
      int p = rpos[b * RD + r];
      bool dup = false;
      for (int r2 = r + 1; r2 < RD; ++r2) dup |= (rpos[b * RD + r2] == p);
      int slot = b * CAND_PER_BATCH + CAND_SCAN + r;
      cand_val[slot] = dup ? FLT_MAX : s;       // numpy scatter: last duplicate wins
      cand_idx[slot] = dup ? INT_MAX : p;
    }
  }
}

__global__ __launch_bounds__(256)
void scan_kernel(const float* __restrict__ memory, const float* __restrict__ xi,
                 const int* __restrict__ rpos,
                 float* __restrict__ cand_val, int* __restrict__ cand_idx) {
  const int b = blockIdx.y;
  const int chunk = blockIdx.x;
  const int t = threadIdx.x;      // 256 = 8 half-wave groups of 32 lanes
  const int grp = t >> 5, lane = t & 31;

  int rp[RD];
  #pragma unroll
  for (int r = 0; r < RD; ++r) rp[r] = rpos[b * RD + r];

  const float4 qv = *(const float4*)(xi + b * XI_STRIDE + lane * 4);

  float bv[8]; int bi[8];
  #pragma unroll
  for (int j = 0; j < 8; ++j) { bv[j] = FLT_MAX; bi[j] = INT_MAX; }

  const float* memB = memory + (size_t)b * MEMN * WD;
  const int rowBase = chunk * ROWS_PER_CHUNK;

  for (int i = 0; i < ROWS_PER_CHUNK / GROUPS; ++i) {
    const int m = rowBase + i * GROUPS + grp;
    const float4 mv = *(const float4*)(memB + (size_t)m * WD + lane * 4);
    // score = |m|^2 - 2 m.q  (|q|^2 constant per batch, irrelevant to argmin)
    float s = mv.x * (mv.x - 2.f * qv.x) + mv.y * (mv.y - 2.f * qv.y)
            + mv.z * (mv.z - 2.f * qv.z) + mv.w * (mv.w - 2.f * qv.w);
    #pragma unroll
    for (int off = 16; off; off >>= 1) s += __shfl_xor(s, off);  // 32-lane reduce
    if (lane == 0) {
      bool skip = false;
      #pragma unroll
      for (int r = 0; r < RD; ++r) skip |= (m == rp[r]);   // scattered rows: stale score
      if (!skip && (s < bv[7] || (s == bv[7] && m < bi[7]))) TOP8_INSERT(bv, bi, s, m);
    }
  }
  if (lane == 0) {
    const int base = b * CAND_PER_BATCH + chunk * (GROUPS * 8) + grp * 8;
    #pragma unroll
    for (int j = 0; j < 8; ++j) { cand_val[base + j] = bv[j]; cand_idx[base + j] = bi[j]; }
  }
}

__global__ __launch_bounds__(128)
void final_kernel(const float* __restrict__ cand_val, const int* __restrict__ cand_idx,
                  const float* __restrict__ memory, const float* __restrict__ new_rv,
                  const int* __restrict__ rpos, float* __restrict__ out) {
  const int b = blockIdx.x, t = threadIdx.x;  // 128
  __shared__ float lv[128][8];
  __shared__ int   li[128][8];
  __shared__ int   posS[KSEL], srcS[KSEL];

  float bv[8]; int bi[8];
  #pragma unroll
  for (int j = 0; j < 8; ++j) { bv[j] = FLT_MAX; bi[j] = INT_MAX; }

  for (int e = t; e < CAND_REAL; e += 128) {
    float v = cand_val[b * CAND_PER_BATCH + e];
    int   i = cand_idx[b * CAND_PER_BATCH + e];
    if (v < bv[7] || (v == bv[7] && i < bi[7])) TOP8_INSERT(bv, bi, v, i);
  }
  #pragma unroll
  for (int j = 0; j < 8; ++j) { lv[t][j] = bv[j]; li[t][j] = bi[j]; }
  __syncthreads();

  for (int stride = 64; stride >= 1; stride >>= 1) {
    if (t < stride) {
      #pragma unroll
      for (int j = 0; j < 8; ++j) {
        float v = lv[t + stride][j]; int i = li[t + stride][j];
        if (v < bv[7] || (v == bv[7] && i < bi[7])) TOP8_INSERT(bv, bi, v, i);
      }
      #pragma unroll
      for (int j = 0; j < 8; ++j) { lv[t][j] = bv[j]; li[t][j] = bi[j]; }
    }
    __syncthreads();
  }

  if (t < KSEL) {
    int p = li[0][t];
    int src = -1;
    for (int r = 0; r < RD; ++r) if (rpos[b * RD + r] == p) src = r;  // last wins
    posS[t] = p; srcS[t] = src;
  }
  __syncthreads();

  for (int e = t; e < KSEL * WD; e += 128) {
    int k = e >> 7, w = e & 127;
    int p = posS[k], src = srcS[k];
    float val = (src >= 0) ? new_rv[(b * RD + src) * WD + w]
                           : memory[((size_t)b * MEMN + p) * WD + w];
    out[b * KSEL * WD + e] = val;
  }
}

extern "C" void kernel_launch(void* const* d_in, const int* in_sizes, int n_in,
                              void* d_out, int out_size, void* d_ws, size_t ws_size,
                              hipStream_t stream) {
  const float* x      = (const float*)d_in[0];
  const float* Wif    = (const float*)d_in[1];
  const float* bif    = (const float*)d_in[2];
  const float* memory = (const float*)d_in[3];
  const float* rw     = (const float*)d_in[4];
  const float* rv     = (const float*)d_in[5];
  const int*   rpos   = (const int*)d_in[6];
  // d_in[7] (last_used_mem) is unused: reference drops that gathered row.

  float* ws       = (float*)d_ws;
  float* xi       = ws;                                   // BD*XI_STRIDE = 8704 floats
  float* new_rv   = xi + BD * XI_STRIDE;                  // BD*RD*WD = 36864 floats
  float* cand_val = new_rv + BD * RD * WD;                // BD*CAND_PER_BATCH floats
  int*   cand_idx = (int*)(cand_val + BD * CAND_PER_BATCH);
  float* out      = (float*)d_out;

  xi_kernel<<<dim3(BD), dim3(320), 0, stream>>>(x, Wif, bif, xi);
  prep_kernel<<<dim3(BD), dim3(WD), 0, stream>>>(xi, rw, rv, new_rv);
  fixup_kernel<<<dim3(BD), dim3(64), 0, stream>>>(xi, new_rv, rpos, cand_val, cand_idx);
  scan_kernel<<<dim3(NCHUNK, BD), dim3(256), 0, stream>>>(memory, xi, rpos, cand_val, cand_idx);
  final_kernel<<<dim3(BD), dim3(128), 0, stream>>>(cand_val, cand_idx, memory, new_rv, rpos, out);
}

// Round 2
// 269.541 us; speedup vs baseline: 1.1679x; 1.1679x over previous
//
#include <hip/hip_runtime.h>
#include <float.h>
#include <limits.h>

#define MEMN 65536
#define WD 128
#define KSEL 8
#define RD 9
#define BD 32
#define IND 512
#define IFACE 266
#define XI_STRIDE 272   // pad 266 -> 272 floats so each batch row is 16B-aligned

#define NCHUNK 128
#define ROWS_PER_CHUNK 512
#define CAND_SCAN (NCHUNK * KSEL)         // 1024 (top-8 per chunk)
#define CAND_REAL (CAND_SCAN + RD)        // 1033
#define CAND_PER_BATCH 1040               // padded

// Sorted ascending (val, idx) top-8 insert; fully unrolled -> registers only.
#define TOP8_INSERT(bv, bi, vin, iin)                                  \
  { float _v = (vin); int _i = (iin);                                  \
    _Pragma("unroll")                                                  \
    for (int _j = 0; _j < 8; ++_j) {                                   \
      bool _b = (_v < bv[_j]) || (_v == bv[_j] && _i < bi[_j]);        \
      float _tv = bv[_j]; int _ti = bi[_j];                            \
      bv[_j] = _b ? _v : _tv;  bi[_j] = _b ? _i : _ti;                 \
      _v = _b ? _tv : _v;      _i = _b ? _ti : _i;                     \
    } }

__global__ __launch_bounds__(320)
void xi_kernel(const float* __restrict__ x, const float* __restrict__ Wif,
               const float* __restrict__ bif, float* __restrict__ xi) {
  const int b = blockIdx.x;
  const int c = threadIdx.x;
  if (c >= IFACE) return;
  float acc = bif[c];
  const float* xr = x + b * IND;
  for (int k = 0; k < IND; ++k)
    acc += xr[k] * Wif[k * IFACE + c];
  xi[b * XI_STRIDE + c] = acc;
}

__global__ __launch_bounds__(WD)
void prep_kernel(const float* __restrict__ xi, const float* __restrict__ read_weights,
                 const float* __restrict__ read_vectors, float* __restrict__ new_rv) {
  const int b = blockIdx.x;
  const int t = threadIdx.x;   // 128
  __shared__ float ww[RD];
  if (t < RD) {
    float g  = 1.f / (1.f + __expf(-xi[b * XI_STRIDE + 2 * WD + t]));
    float wg = 1.f / (1.f + __expf(-xi[b * XI_STRIDE + (IFACE - 1)]));
    float rw = read_weights[b * RD + t];
    ww[t] = wg * (g * rw + (1.f - g));
  }
  __syncthreads();
  const float wv = xi[b * XI_STRIDE + WD + t];
  #pragma unroll
  for (int r = 0; r < RD; ++r)
    new_rv[(b * RD + r) * WD + t] = read_vectors[(b * RD + r) * WD + t] + ww[r] * wv;
}

__global__ __launch_bounds__(64)
void fixup_kernel(const float* __restrict__ xi, const float* __restrict__ new_rv,
                  const int* __restrict__ rpos,
                  float* __restrict__ cand_val, int* __restrict__ cand_idx) {
  const int b = blockIdx.x;
  const int lane = threadIdx.x;   // 64
  const float q0 = xi[b * XI_STRIDE + lane * 2];
  const float q1 = xi[b * XI_STRIDE + lane * 2 + 1];
  for (int r = 0; r < RD; ++r) {
    const float* row = new_rv + (b * RD + r) * WD;
    float m0 = row[lane * 2], m1 = row[lane * 2 + 1];
    float s = m0 * (m0 - 2.f * q0) + m1 * (m1 - 2.f * q1);
    #pragma unroll
    for (int off = 32; off; off >>= 1) s += __shfl_xor(s, off);
    if (lane == 0) {
      int p = rpos[b * RD + r];
      bool dup = false;
      for (int r2 = r + 1; r2 < RD; ++r2) dup |= (rpos[b * RD + r2] == p);
      int slot = b * CAND_PER_BATCH + CAND_SCAN + r;
      cand_val[slot] = dup ? FLT_MAX : s;       // numpy scatter: last duplicate wins
      cand_idx[slot] = dup ? INT_MAX : p;
    }
  }
}

// 256 threads = 16 groups of 16 lanes. Each group scores 4 rows per iteration:
// lane ln holds cols [ln*4..ln*4+3] and [64+ln*4..64+ln*4+3] of each row
// (2x float4 per row, 8 loads in flight per lane per iteration).
__global__ __launch_bounds__(256)
void scan_kernel(const float* __restrict__ memory, const float* __restrict__ xi,
                 const int* __restrict__ rpos,
                 float* __restrict__ cand_val, int* __restrict__ cand_idx) {
  const int b = blockIdx.y;
  const int chunk = blockIdx.x;
  const int t = threadIdx.x;
  const int sg = t >> 4;        // 0..15
  const int ln = t & 15;        // 0..15
  const int chunkBase = chunk * ROWS_PER_CHUNK;

  // 32-bit stale mask: bit (i*4+j) <=> row chunkBase + i*64 + sg*4 + j is scattered.
  unsigned stale = 0u;
  #pragma unroll
  for (int r = 0; r < RD; ++r) {
    int d = rpos[b * RD + r] - chunkBase;
    if (d >= 0 && d < ROWS_PER_CHUNK && ((((unsigned)d) >> 2) & 15u) == (unsigned)sg)
      stale |= 1u << (((((unsigned)d) >> 6) << 2) | (((unsigned)d) & 3u));
  }

  const float4 ql = *(const float4*)(xi + b * XI_STRIDE + ln * 4);
  const float4 qh = *(const float4*)(xi + b * XI_STRIDE + 64 + ln * 4);
  const float tlx = 2.f * ql.x, tly = 2.f * ql.y, tlz = 2.f * ql.z, tlw = 2.f * ql.w;
  const float thx = 2.f * qh.x, thy = 2.f * qh.y, thz = 2.f * qh.z, thw = 2.f * qh.w;

  float bv[8]; int bi[8];
  #pragma unroll
  for (int j = 0; j < 8; ++j) { bv[j] = FLT_MAX; bi[j] = INT_MAX; }

  const float* memB = memory + (size_t)b * MEMN * WD;

  #pragma unroll 1
  for (int i = 0; i < 8; ++i) {
    const int m0 = chunkBase + i * 64 + sg * 4;
    const float* p = memB + (size_t)m0 * WD + ln * 4;
    const float4 a0 = *(const float4*)(p);
    const float4 c0 = *(const float4*)(p + 64);
    const float4 a1 = *(const float4*)(p + WD);
    const float4 c1 = *(const float4*)(p + WD + 64);
    const float4 a2 = *(const float4*)(p + 2 * WD);
    const float4 c2 = *(const float4*)(p + 2 * WD + 64);
    const float4 a3 = *(const float4*)(p + 3 * WD);
    const float4 c3 = *(const float4*)(p + 3 * WD + 64);

    float s0 = a0.x*(a0.x-tlx)+a0.y*(a0.y-tly)+a0.z*(a0.z-tlz)+a0.w*(a0.w-tlw)
             + c0.x*(c0.x-thx)+c0.y*(c0.y-thy)+c0.z*(c0.z-thz)+c0.w*(c0.w-thw);
    float s1 = a1.x*(a1.x-tlx)+a1.y*(a1.y-tly)+a1.z*(a1.z-tlz)+a1.w*(a1.w-tlw)
             + c1.x*(c1.x-thx)+c1.y*(c1.y-thy)+c1.z*(c1.z-thz)+c1.w*(c1.w-thw);
    float s2 = a2.x*(a2.x-tlx)+a2.y*(a2.y-tly)+a2.z*(a2.z-tlz)+a2.w*(a2.w-tlw)
             + c2.x*(c2.x-thx)+c2.y*(c2.y-thy)+c2.z*(c2.z-thz)+c2.w*(c2.w-thw);
    float s3 = a3.x*(a3.x-tlx)+a3.y*(a3.y-tly)+a3.z*(a3.z-tlz)+a3.w*(a3.w-tlw)
             + c3.x*(c3.x-thx)+c3.y*(c3.y-thy)+c3.z*(c3.z-thz)+c3.w*(c3.w-thw);

    // 4 independent 16-lane reduces (xor 8,4,2,1) -> ILP
    #pragma unroll
    for (int off = 8; off; off >>= 1) {
      s0 += __shfl_xor(s0, off);
      s1 += __shfl_xor(s1, off);
      s2 += __shfl_xor(s2, off);
      s3 += __shfl_xor(s3, off);
    }

    if (ln == 0) {
      const unsigned sm = stale >> (i * 4);
      if (!(sm & 1u) && (s0 < bv[7] || (s0 == bv[7] && m0     < bi[7]))) TOP8_INSERT(bv, bi, s0, m0);
      if (!(sm & 2u) && (s1 < bv[7] || (s1 == bv[7] && m0 + 1 < bi[7]))) TOP8_INSERT(bv, bi, s1, m0 + 1);
      if (!(sm & 4u) && (s2 < bv[7] || (s2 == bv[7] && m0 + 2 < bi[7]))) TOP8_INSERT(bv, bi, s2, m0 + 2);
      if (!(sm & 8u) && (s3 < bv[7] || (s3 == bv[7] && m0 + 3 < bi[7]))) TOP8_INSERT(bv, bi, s3, m0 + 3);
    }
  }

  // Merge 16 group-top8s -> chunk top8 in LDS.
  __shared__ float lv[16][8];
  __shared__ int   li[16][8];
  if (ln == 0) {
    #pragma unroll
    for (int j = 0; j < 8; ++j) { lv[sg][j] = bv[j]; li[sg][j] = bi[j]; }
  }
  __syncthreads();
  for (int s = 8; s >= 1; s >>= 1) {
    if (t < s) {
      float mv[8]; int mi[8];
      #pragma unroll
      for (int j = 0; j < 8; ++j) { mv[j] = lv[t][j]; mi[j] = li[t][j]; }
      #pragma unroll
      for (int j = 0; j < 8; ++j) {
        float v = lv[t + s][j]; int i = li[t + s][j];
        if (v < mv[7] || (v == mv[7] && i < mi[7])) TOP8_INSERT(mv, mi, v, i);
      }
      #pragma unroll
      for (int j = 0; j < 8; ++j) { lv[t][j] = mv[j]; li[t][j] = mi[j]; }
    }
    __syncthreads();
  }
  if (t < 8) {
    cand_val[b * CAND_PER_BATCH + chunk * 8 + t] = lv[0][t];
    cand_idx[b * CAND_PER_BATCH + chunk * 8 + t] = li[0][t];
  }
}

__global__ __launch_bounds__(128)
void final_kernel(const float* __restrict__ cand_val, const int* __restrict__ cand_idx,
                  const float* __restrict__ memory, const float* __restrict__ new_rv,
                  const int* __restrict__ rpos, float* __restrict__ out) {
  const int b = blockIdx.x, t = threadIdx.x;  // 128
  __shared__ float lv[128][8];
  __shared__ int   li[128][8];
  __shared__ int   posS[KSEL], srcS[KSEL];

  float bv[8]; int bi[8];
  #pragma unroll
  for (int j = 0; j < 8; ++j) { bv[j] = FLT_MAX; bi[j] = INT_MAX; }

  for (int e = t; e < CAND_REAL; e += 128) {
    float v = cand_val[b * CAND_PER_BATCH + e];
    int   i = cand_idx[b * CAND_PER_BATCH + e];
    if (v < bv[7] || (v == bv[7] && i < bi[7])) TOP8_INSERT(bv, bi, v, i);
  }
  #pragma unroll
  for (int j = 0; j < 8; ++j) { lv[t][j] = bv[j]; li[t][j] = bi[j]; }
  __syncthreads();

  for (int stride = 64; stride >= 1; stride >>= 1) {
    if (t < stride) {
      #pragma unroll
      for (int j = 0; j < 8; ++j) {
        float v = lv[t + stride][j]; int i = li[t + stride][j];
        if (v < bv[7] || (v == bv[7] && i < bi[7])) TOP8_INSERT(bv, bi, v, i);
      }
      #pragma unroll
      for (int j = 0; j < 8; ++j) { lv[t][j] = bv[j]; li[t][j] = bi[j]; }
    }
    __syncthreads();
  }

  if (t < KSEL) {
    int p = li[0][t];
    int src = -1;
    for (int r = 0; r < RD; ++r) if (rpos[b * RD + r] == p) src = r;  // last wins
    posS[t] = p; srcS[t] = src;
  }
  __syncthreads();

  for (int e = t; e < KSEL * WD; e += 128) {
    int k = e >> 7, w = e & 127;
    int p = posS[k], src = srcS[k];
    float val = (src >= 0) ? new_rv[(b * RD + src) * WD + w]
                           : memory[((size_t)b * MEMN + p) * WD + w];
    out[b * KSEL * WD + e] = val;
  }
}

extern "C" void kernel_launch(void* const* d_in, const int* in_sizes, int n_in,
                              void* d_out, int out_size, void* d_ws, size_t ws_size,
                              hipStream_t stream) {
  const float* x      = (const float*)d_in[0];
  const float* Wif    = (const float*)d_in[1];
  const float* bif    = (const float*)d_in[2];
  const float* memory = (const float*)d_in[3];
  const float* rw     = (const float*)d_in[4];
  const float* rv     = (const float*)d_in[5];
  const int*   rpos   = (const int*)d_in[6];
  // d_in[7] (last_used_mem) is unused: reference drops that gathered row.

  float* ws       = (float*)d_ws;
  float* xi       = ws;                                   // BD*XI_STRIDE floats
  float* new_rv   = xi + BD * XI_STRIDE;                  // BD*RD*WD floats
  float* cand_val = new_rv + BD * RD * WD;                // BD*CAND_PER_BATCH floats
  int*   cand_idx = (int*)(cand_val + BD * CAND_PER_BATCH);
  float* out      = (float*)d_out;

  xi_kernel<<<dim3(BD), dim3(320), 0, stream>>>(x, Wif, bif, xi);
  prep_kernel<<<dim3(BD), dim3(WD), 0, stream>>>(xi, rw, rv, new_rv);
  fixup_kernel<<<dim3(BD), dim3(64), 0, stream>>>(xi, new_rv, rpos, cand_val, cand_idx);
  scan_kernel<<<dim3(NCHUNK, BD), dim3(256), 0, stream>>>(memory, xi, rpos, cand_val, cand_idx);
  final_kernel<<<dim3(BD), dim3(128), 0, stream>>>(cand_val, cand_idx, memory, new_rv, rpos, out);
}

// Round 4
// 241.699 us; speedup vs baseline: 1.3024x; 1.1152x over previous
//
#include <hip/hip_runtime.h>
#include <float.h>
#include <limits.h>

#define MEMN 65536
#define WD 128
#define KSEL 8
#define RD 9
#define BD 32
#define IND 512
#define IFACE 266
#define XI_STRIDE 272   // pad 266 -> 272 floats (1088B, 16B-aligned rows)

#define KSEG 8
#define KSEG_LEN (IND / KSEG)            // 64

#define NCHUNK 64
#define ROWS_PER_CHUNK 1024
#define CAND_SCAN (NCHUNK * KSEL)        // 512
#define CAND_REAL (CAND_SCAN + RD)       // 521
#define CAND_PER_BATCH 528               // padded

typedef float fvec4 __attribute__((ext_vector_type(4)));

// Sorted ascending (val, idx) top-8 insert; fully unrolled -> registers only.
#define TOP8_INSERT(bv, bi, vin, iin)                                  \
  { float _v = (vin); int _i = (iin);                                  \
    _Pragma("unroll")                                                  \
    for (int _j = 0; _j < 8; ++_j) {                                   \
      bool _b = (_v < bv[_j]) || (_v == bv[_j] && _i < bi[_j]);        \
      float _tv = bv[_j]; int _ti = bi[_j];                            \
      bv[_j] = _b ? _v : _tv;  bi[_j] = _b ? _i : _ti;                 \
      _v = _b ? _tv : _v;      _i = _b ? _ti : _i;                     \
    } }

__device__ __forceinline__ fvec4 ntload(const void* p) {
  return __builtin_nontemporal_load((const fvec4*)p);
}

// Split-K partial GEMM: block (b, seg) computes 64-deep partials for all 266 cols.
__global__ __launch_bounds__(288)
void xi_part_kernel(const float* __restrict__ x, const float* __restrict__ Wif,
                    float* __restrict__ xi_part) {
  const int b = blockIdx.x, seg = blockIdx.y, c = threadIdx.x;
  if (c >= IFACE) return;
  const float* xr = x + b * IND + seg * KSEG_LEN;       // block-uniform -> s_loads
  const float* wp = Wif + (size_t)(seg * KSEG_LEN) * IFACE + c;
  float a0 = 0.f, a1 = 0.f, a2 = 0.f, a3 = 0.f;
  #pragma unroll
  for (int k = 0; k < KSEG_LEN; k += 4) {
    a0 += xr[k]     * wp[(size_t)k * IFACE];
    a1 += xr[k + 1] * wp[(size_t)(k + 1) * IFACE];
    a2 += xr[k + 2] * wp[(size_t)(k + 2) * IFACE];
    a3 += xr[k + 3] * wp[(size_t)(k + 3) * IFACE];
  }
  xi_part[(b * KSEG + seg) * XI_STRIDE + c] = (a0 + a1) + (a2 + a3);
}

// Fused: xi reduce (+bias) -> gates/new_rv -> fixup candidate scores.
__global__ __launch_bounds__(320)
void head_kernel(const float* __restrict__ xi_part, const float* __restrict__ bif,
                 const float* __restrict__ read_weights, const float* __restrict__ read_vectors,
                 const int* __restrict__ rpos,
                 float* __restrict__ xi, float* __restrict__ new_rv,
                 float* __restrict__ cand_val, int* __restrict__ cand_idx) {
  const int b = blockIdx.x, t = threadIdx.x;  // 320
  __shared__ float xiS[IFACE];
  __shared__ float wwS[RD];
  __shared__ float nvS[RD][WD];

  // phase 0: reduce split-K partials
  if (t < IFACE) {
    float acc = bif[t];
    #pragma unroll
    for (int s = 0; s < KSEG; ++s)
      acc += xi_part[(b * KSEG + s) * XI_STRIDE + t];
    xiS[t] = acc;
    xi[b * XI_STRIDE + t] = acc;   // scan reads query cols [0,128)
  }
  __syncthreads();

  // phase 1: write weights
  if (t < RD) {
    float g  = 1.f / (1.f + __expf(-xiS[2 * WD + t]));
    float wg = 1.f / (1.f + __expf(-xiS[IFACE - 1]));
    wwS[t] = wg * (g * read_weights[b * RD + t] + (1.f - g));
  }
  __syncthreads();

  // phase 2: new_rv
  if (t < WD) {
    const float wv = xiS[WD + t];
    #pragma unroll
    for (int r = 0; r < RD; ++r) {
      float nv = read_vectors[(b * RD + r) * WD + t] + wwS[r] * wv;
      nvS[r][t] = nv;
      new_rv[(b * RD + r) * WD + t] = nv;
    }
  }
  __syncthreads();

  // phase 3: fixup scores for the 9 scattered rows (wave 0 only)
  if (t < 64) {
    const int lane = t;
    const float q0 = xiS[lane * 2], q1 = xiS[lane * 2 + 1];
    for (int r = 0; r < RD; ++r) {
      float m0 = nvS[r][lane * 2], m1 = nvS[r][lane * 2 + 1];
      float s = m0 * (m0 - 2.f * q0) + m1 * (m1 - 2.f * q1);
      #pragma unroll
      for (int off = 32; off; off >>= 1) s += __shfl_xor(s, off);
      if (lane == 0) {
        int p = rpos[b * RD + r];
        bool dup = false;
        for (int r2 = r + 1; r2 < RD; ++r2) dup |= (rpos[b * RD + r2] == p);
        int slot = b * CAND_PER_BATCH + CAND_SCAN + r;
        cand_val[slot] = dup ? FLT_MAX : s;   // numpy scatter: last duplicate wins
        cand_idx[slot] = dup ? INT_MAX : p;
      }
    }
  }
}

// 256 threads = 4 waves; wave handles 16 rows/iter via 4-lane groups.
// Lane ln of a group owns row bytes ln*16 + j*64 (j=0..7) -> 8 nt float4 loads.
__global__ __launch_bounds__(256)
void scan_kernel(const float* __restrict__ memory, const float* __restrict__ xi,
                 const int* __restrict__ rpos,
                 float* __restrict__ cand_val, int* __restrict__ cand_idx) {
  const int b = blockIdx.y, chunk = blockIdx.x;
  const int t = threadIdx.x;
  const int w = t >> 6, l = t & 63, g = l >> 2, ln = l & 3;
  const int chunkBase = chunk * ROWS_PER_CHUNK;

  int rp[RD];
  #pragma unroll
  for (int r = 0; r < RD; ++r) rp[r] = rpos[b * RD + r];

  // 2*query, this lane's 32 columns (8 vec4s)
  fvec4 tq[8];
  #pragma unroll
  for (int j = 0; j < 8; ++j) {
    fvec4 q = *(const fvec4*)(xi + b * XI_STRIDE + j * 16 + ln * 4);
    tq[j] = q * 2.f;
  }

  float bv[8]; int bi[8];
  #pragma unroll
  for (int j = 0; j < 8; ++j) { bv[j] = FLT_MAX; bi[j] = INT_MAX; }

  const char* memB = (const char*)memory + (size_t)b * MEMN * (WD * 4);

  #pragma unroll 2
  for (int i = 0; i < ROWS_PER_CHUNK / 64; ++i) {       // 16 iterations
    const int m = chunkBase + i * 64 + w * 16 + g;
    const char* p = memB + (size_t)m * (WD * 4) + ln * 16;
    float sA = 0.f, sB = 0.f;
    #pragma unroll
    for (int j = 0; j < 8; j += 2) {
      fvec4 m0 = ntload(p + j * 64);
      fvec4 m1 = ntload(p + (j + 1) * 64);
      sA += m0.x * (m0.x - tq[j].x) + m0.y * (m0.y - tq[j].y)
          + m0.z * (m0.z - tq[j].z) + m0.w * (m0.w - tq[j].w);
      sB += m1.x * (m1.x - tq[j + 1].x) + m1.y * (m1.y - tq[j + 1].y)
          + m1.z * (m1.z - tq[j + 1].z) + m1.w * (m1.w - tq[j + 1].w);
    }
    float s = sA + sB;
    s += __shfl_xor(s, 1);
    s += __shfl_xor(s, 2);        // lanes ln==0 hold full row score
    if (ln == 0) {
      bool skip = false;
      #pragma unroll
      for (int r = 0; r < RD; ++r) skip |= (m == rp[r]);  // scattered rows: stale
      if (!skip && (s < bv[7] || (s == bv[7] && m < bi[7]))) TOP8_INSERT(bv, bi, s, m);
    }
  }

  // Merge 64 group-top8s (4 waves x 16 groups) -> chunk top8.
  __shared__ float lv[64][8];
  __shared__ int   li[64][8];
  if (ln == 0) {
    #pragma unroll
    for (int j = 0; j < 8; ++j) { lv[w * 16 + g][j] = bv[j]; li[w * 16 + g][j] = bi[j]; }
  }
  __syncthreads();
  for (int s = 32; s >= 1; s >>= 1) {
    if (t < s) {
      float mv[8]; int mi[8];
      #pragma unroll
      for (int j = 0; j < 8; ++j) { mv[j] = lv[t][j]; mi[j] = li[t][j]; }
      #pragma unroll
      for (int j = 0; j < 8; ++j) {
        float v = lv[t + s][j]; int i = li[t + s][j];
        if (v < mv[7] || (v == mv[7] && i < mi[7])) TOP8_INSERT(mv, mi, v, i);
      }
      #pragma unroll
      for (int j = 0; j < 8; ++j) { lv[t][j] = mv[j]; li[t][j] = mi[j]; }
    }
    __syncthreads();
  }
  if (t < 8) {
    cand_val[b * CAND_PER_BATCH + chunk * 8 + t] = lv[0][t];
    cand_idx[b * CAND_PER_BATCH + chunk * 8 + t] = li[0][t];
  }
}

__global__ __launch_bounds__(128)
void final_kernel(const float* __restrict__ cand_val, const int* __restrict__ cand_idx,
                  const float* __restrict__ memory, const float* __restrict__ new_rv,
                  const int* __restrict__ rpos, float* __restrict__ out) {
  const int b = blockIdx.x, t = threadIdx.x;  // 128
  __shared__ float lv[128][8];
  __shared__ int   li[128][8];
  __shared__ int   posS[KSEL], srcS[KSEL];

  float bv[8]; int bi[8];
  #pragma unroll
  for (int j = 0; j < 8; ++j) { bv[j] = FLT_MAX; bi[j] = INT_MAX; }

  for (int e = t; e < CAND_REAL; e += 128) {
    float v = cand_val[b * CAND_PER_BATCH + e];
    int   i = cand_idx[b * CAND_PER_BATCH + e];
    if (v < bv[7] || (v == bv[7] && i < bi[7])) TOP8_INSERT(bv, bi, v, i);
  }
  #pragma unroll
  for (int j = 0; j < 8; ++j) { lv[t][j] = bv[j]; li[t][j] = bi[j]; }
  __syncthreads();

  for (int stride = 64; stride >= 1; stride >>= 1) {
    if (t < stride) {
      #pragma unroll
      for (int j = 0; j < 8; ++j) {
        float v = lv[t + stride][j]; int i = li[t + stride][j];
        if (v < bv[7] || (v == bv[7] && i < bi[7])) TOP8_INSERT(bv, bi, v, i);
      }
      #pragma unroll
      for (int j = 0; j < 8; ++j) { lv[t][j] = bv[j]; li[t][j] = bi[j]; }
    }
    __syncthreads();
  }

  if (t < KSEL) {
    int p = li[0][t];
    int src = -1;
    for (int r = 0; r < RD; ++r) if (rpos[b * RD + r] == p) src = r;  // last wins
    posS[t] = p; srcS[t] = src;
  }
  __syncthreads();

  for (int e = t; e < KSEL * WD; e += 128) {
    int k = e >> 7, w = e & 127;
    int p = posS[k], src = srcS[k];
    float val = (src >= 0) ? new_rv[(b * RD + src) * WD + w]
                           : memory[((size_t)b * MEMN + p) * WD + w];
    out[b * KSEL * WD + e] = val;
  }
}

extern "C" void kernel_launch(void* const* d_in, const int* in_sizes, int n_in,
                              void* d_out, int out_size, void* d_ws, size_t ws_size,
                              hipStream_t stream) {
  const float* x      = (const float*)d_in[0];
  const float* Wif    = (const float*)d_in[1];
  const float* bif    = (const float*)d_in[2];
  const float* memory = (const float*)d_in[3];
  const float* rw     = (const float*)d_in[4];
  const float* rv     = (const float*)d_in[5];
  const int*   rpos   = (const int*)d_in[6];
  // d_in[7] (last_used_mem) unused: reference drops that gathered row.

  float* ws       = (float*)d_ws;
  float* xi_part  = ws;                                   // BD*KSEG*XI_STRIDE floats
  float* xi       = xi_part + BD * KSEG * XI_STRIDE;      // BD*XI_STRIDE
  float* new_rv   = xi + BD * XI_STRIDE;                  // BD*RD*WD
  float* cand_val = new_rv + BD * RD * WD;                // BD*CAND_PER_BATCH
  int*   cand_idx = (int*)(cand_val + BD * CAND_PER_BATCH);
  float* out      = (float*)d_out;

  xi_part_kernel<<<dim3(BD, KSEG), dim3(288), 0, stream>>>(x, Wif, xi_part);
  head_kernel<<<dim3(BD), dim3(320), 0, stream>>>(xi_part, bif, rw, rv, rpos,
                                                  xi, new_rv, cand_val, cand_idx);
  scan_kernel<<<dim3(NCHUNK, BD), dim3(256), 0, stream>>>(memory, xi, rpos, cand_val, cand_idx);
  final_kernel<<<dim3(BD), dim3(128), 0, stream>>>(cand_val, cand_idx, memory, new_rv, rpos, out);
}